// Round 5
// baseline (24809.683 us; speedup 1.0000x reference)
//
#include <hip/hip_runtime.h>
#include <hip/hip_bf16.h>
#include <math.h>

#define BATCH 16
#define C_IN 8
#define C_MID 64
#define C_OUT 128
#define LEN 512
#define TSTEPS 50
#define HZN 8

// ---------------------------------------------------------------------------
// Encoder conv1d (k=3, same-pad) + activation, fp64 accumulation/output.
// One thread per (b, o, l). ACT: 0=none, 1=relu, 2=tanh.
// ---------------------------------------------------------------------------
template <typename Tin, int Ci, int Cout, int ACT>
__global__ __launch_bounds__(256)
void enc_conv(const Tin* __restrict__ x, const float* __restrict__ w,
              const float* __restrict__ bias, double* __restrict__ y) {
    int idx = blockIdx.x * 256 + threadIdx.x;
    if (idx >= BATCH * Cout * LEN) return;
    const int l = idx % LEN;
    const int o = (idx / LEN) % Cout;
    const int b = idx / (LEN * Cout);

    double acc = (double)bias[o];
    #pragma unroll 4
    for (int i = 0; i < Ci; ++i) {
        const float* wp = &w[(o * Ci + i) * 3];
        const Tin* xp = &x[((size_t)b * Ci + i) * LEN + l];
        if (l > 0)       acc += (double)wp[0] * (double)xp[-1];
                         acc += (double)wp[1] * (double)xp[0];
        if (l < LEN - 1) acc += (double)wp[2] * (double)xp[1];
    }
    if (ACT == 1) acc = acc > 0.0 ? acc : 0.0;
    else if (ACT == 2) acc = tanh(acc);
    y[idx] = acc;
}

__global__ void zero_f64(double* __restrict__ p, int n) {
    int i = blockIdx.x * 256 + threadIdx.x;
    if (i < n) p[i] = 0.0;
}

// ---------------------------------------------------------------------------
// One coRNN step, fp64. One thread per (b, o, l); direct global reads.
//   pre    = tanh(conv(hy,wy)+by + conv(hz,wz)+bz + xdrive)
//   hz_new = hz + 0.5*(pre - omega*hy - alpha*hz)
//   hy_new = hy + 0.5*hz_new ;  yseq[t] = f32(hy_new)
// ---------------------------------------------------------------------------
__global__ __launch_bounds__(256)
void rnn_step(const double* __restrict__ hy, const double* __restrict__ hz,
              const double* __restrict__ om, const double* __restrict__ al,
              const double* __restrict__ xd,
              const float* __restrict__ wy, const float* __restrict__ by,
              const float* __restrict__ wz, const float* __restrict__ bz,
              double* __restrict__ hyo, double* __restrict__ hzo,
              float* __restrict__ yseq, int t) {
    int idx = blockIdx.x * 256 + threadIdx.x;  // total BATCH*C_OUT*LEN = 1M
    const int l = idx & (LEN - 1);
    const int o = (idx >> 9) & (C_OUT - 1);
    const int b = idx >> 16;
    const size_t base = (size_t)b * C_OUT * LEN;

    double accy = (double)by[o];
    double accz = (double)bz[o];
    #pragma unroll 4
    for (int i = 0; i < C_OUT; ++i) {
        const float* wyp = &wy[(o * C_OUT + i) * 3];
        const float* wzp = &wz[(o * C_OUT + i) * 3];
        const double* hyp = &hy[base + (size_t)i * LEN + l];
        const double* hzp = &hz[base + (size_t)i * LEN + l];
        if (l > 0) {
            accy += (double)wyp[0] * hyp[-1];
            accz += (double)wzp[0] * hzp[-1];
        }
        accy += (double)wyp[1] * hyp[0];
        accz += (double)wzp[1] * hzp[0];
        if (l < LEN - 1) {
            accy += (double)wyp[2] * hyp[1];
            accz += (double)wzp[2] * hzp[1];
        }
    }
    const double hyv = hy[idx];
    const double hzv = hz[idx];
    const double pre = tanh(accy + accz + xd[idx]);
    const double hzn = hzv + 0.5 * (pre - om[idx] * hyv - al[idx] * hzv);
    const double hyn = hyv + 0.5 * hzn;
    hzo[idx] = hzn;
    hyo[idx] = hyn;
    yseq[((size_t)(b * TSTEPS + t) * C_OUT + o) * LEN + l] = (float)hyn;
}

// ---------------------------------------------------------------------------
// Readout: feat = mean_L(hy_T); 3-layer MLP (fp64); fp32 predictions.
// ---------------------------------------------------------------------------
__global__ void readout(const double* __restrict__ hyT,
                        const float* __restrict__ fw1, const float* __restrict__ fb1,
                        const float* __restrict__ fw2, const float* __restrict__ fb2,
                        const float* __restrict__ fw3, const float* __restrict__ fb3,
                        float* __restrict__ pred) {
    const int b = blockIdx.x;
    const int t = threadIdx.x;  // 128 threads
    __shared__ double feat[C_OUT];
    __shared__ double h1[64];
    __shared__ double h2[32];

    {
        double s = 0.0;
        const double* p = &hyT[((size_t)b * C_OUT + t) * LEN];
        for (int l = 0; l < LEN; ++l) s += p[l];
        feat[t] = s * (1.0 / LEN);
    }
    __syncthreads();
    if (t < 64) {
        double s = (double)fb1[t];
        for (int i = 0; i < C_OUT; ++i) s += (double)fw1[t * C_OUT + i] * feat[i];
        h1[t] = s > 0.0 ? s : 0.0;
    }
    __syncthreads();
    if (t < 32) {
        double s = (double)fb2[t];
        for (int i = 0; i < 64; ++i) s += (double)fw2[t * 64 + i] * h1[i];
        h2[t] = s > 0.0 ? s : 0.0;
    }
    __syncthreads();
    if (t < HZN) {
        double s = (double)fb3[t];
        for (int i = 0; i < 32; ++i) s += (double)fw3[t * 32 + i] * h2[i];
        pred[b * HZN + t] = (float)s;
    }
}

// ---------------------------------------------------------------------------
extern "C" void kernel_launch(void* const* d_in, const int* in_sizes, int n_in,
                              void* d_out, int out_size, void* d_ws, size_t ws_size,
                              hipStream_t stream) {
    const float* x   = (const float*)d_in[0];
    const float* ow1 = (const float*)d_in[1];  const float* ob1 = (const float*)d_in[2];
    const float* ow2 = (const float*)d_in[3];  const float* ob2 = (const float*)d_in[4];
    const float* ow3 = (const float*)d_in[5];  const float* ob3 = (const float*)d_in[6];
    const float* aw1 = (const float*)d_in[7];  const float* ab1 = (const float*)d_in[8];
    const float* aw2 = (const float*)d_in[9];  const float* ab2 = (const float*)d_in[10];
    const float* aw3 = (const float*)d_in[11]; const float* ab3 = (const float*)d_in[12];
    const float* hw1 = (const float*)d_in[13]; const float* hb1 = (const float*)d_in[14];
    const float* hw2 = (const float*)d_in[15]; const float* hb2 = (const float*)d_in[16];
    const float* hw3 = (const float*)d_in[17]; const float* hb3 = (const float*)d_in[18];
    const float* hw4 = (const float*)d_in[19]; const float* hb4 = (const float*)d_in[20];
    const float* cwy = (const float*)d_in[21]; const float* cby = (const float*)d_in[22];
    const float* cwz = (const float*)d_in[23]; const float* cbz = (const float*)d_in[24];
    const float* cwx = (const float*)d_in[25]; const float* cbx = (const float*)d_in[26];
    const float* fw1 = (const float*)d_in[27]; const float* fb1 = (const float*)d_in[28];
    const float* fw2 = (const float*)d_in[29]; const float* fb2 = (const float*)d_in[30];
    const float* fw3 = (const float*)d_in[31]; const float* fb3 = (const float*)d_in[32];

    float* out  = (float*)d_out;
    float* pred = out;                    // (B, HZN) fp32
    float* yseq = out + BATCH * HZN;      // (B, T, C_OUT, LEN) fp32

    // workspace: 7 fp64 state buffers (8 MB each = 56 MB total).
    // Encoder temps alias hyB/hzB (unused until the recurrence starts).
    const size_t SZ = (size_t)BATCH * C_OUT * LEN;  // 1,048,576 elements
    double* ws  = (double*)d_ws;
    double* om  = ws + 0 * SZ;
    double* al  = ws + 1 * SZ;
    double* xd  = ws + 2 * SZ;
    double* hyA = ws + 3 * SZ;
    double* hzA = ws + 4 * SZ;
    double* hyB = ws + 5 * SZ;
    double* hzB = ws + 6 * SZ;
    double* t1  = hyB;  // (B, C_MID, L) = 4 MB, fits in 8 MB
    double* t2  = hzB;

    const int gm = (BATCH * C_MID * LEN + 255) / 256;  // 2048 blocks
    const int go = (BATCH * C_OUT * LEN + 255) / 256;  // 4096 blocks

    // omega encoder
    enc_conv<float,  C_IN,  C_MID, 1><<<gm, 256, 0, stream>>>(x,  ow1, ob1, t1);
    enc_conv<double, C_MID, C_MID, 1><<<gm, 256, 0, stream>>>(t1, ow2, ob2, t2);
    enc_conv<double, C_MID, C_OUT, 1><<<go, 256, 0, stream>>>(t2, ow3, ob3, om);
    // alpha encoder
    enc_conv<float,  C_IN,  C_MID, 1><<<gm, 256, 0, stream>>>(x,  aw1, ab1, t1);
    enc_conv<double, C_MID, C_MID, 1><<<gm, 256, 0, stream>>>(t1, aw2, ab2, t2);
    enc_conv<double, C_MID, C_OUT, 1><<<go, 256, 0, stream>>>(t2, aw3, ab3, al);
    // hy encoder
    enc_conv<float,  C_IN,  C_MID, 1><<<gm, 256, 0, stream>>>(x,  hw1, hb1, t1);
    enc_conv<double, C_MID, C_MID, 1><<<gm, 256, 0, stream>>>(t1, hw2, hb2, t2);
    enc_conv<double, C_MID, C_MID, 1><<<gm, 256, 0, stream>>>(t2, hw3, hb3, t1);
    enc_conv<double, C_MID, C_OUT, 2><<<go, 256, 0, stream>>>(t1, hw4, hb4, hyA);
    // x drive (no activation)
    enc_conv<float,  C_IN,  C_OUT, 0><<<go, 256, 0, stream>>>(x, cwx, cbx, xd);
    // hz0 = 0
    zero_f64<<<go, 256, 0, stream>>>(hzA, (int)SZ);

    // recurrence (note: step 0 overwrites hyB/hzB, which held encoder temps)
    double* hy_cur = hyA; double* hz_cur = hzA;
    double* hy_nxt = hyB; double* hz_nxt = hzB;
    for (int t = 0; t < TSTEPS; ++t) {
        rnn_step<<<go, 256, 0, stream>>>(hy_cur, hz_cur, om, al, xd,
                                         cwy, cby, cwz, cbz,
                                         hy_nxt, hz_nxt, yseq, t);
        double* sy = hy_cur; hy_cur = hy_nxt; hy_nxt = sy;
        double* sz = hz_cur; hz_cur = hz_nxt; hz_nxt = sz;
    }

    // readout on final hy
    readout<<<BATCH, C_OUT, 0, stream>>>(hy_cur, fw1, fb1, fw2, fb2, fw3, fb3, pred);
}

// Round 6
// 4181.247 us; speedup vs baseline: 5.9336x; 5.9336x over previous
//
#include <hip/hip_runtime.h>
#include <hip/hip_bf16.h>
#include <math.h>

#define BATCH 16
#define C_IN 8
#define C_MID 64
#define C_OUT 128
#define LEN 512
#define TSTEPS 50
#define HZN 8
#define TL 16   // l-tile per block in rnn_step

// ---------------------------------------------------------------------------
// Encoder conv1d (k=3, same-pad) + activation, fp64 accumulation/output.
// One thread per (b, o, l). ACT: 0=none, 1=relu, 2=tanh.
// ---------------------------------------------------------------------------
template <typename Tin, int Ci, int Cout, int ACT>
__global__ __launch_bounds__(256)
void enc_conv(const Tin* __restrict__ x, const float* __restrict__ w,
              const float* __restrict__ bias, double* __restrict__ y) {
    int idx = blockIdx.x * 256 + threadIdx.x;
    if (idx >= BATCH * Cout * LEN) return;
    const int l = idx % LEN;
    const int o = (idx / LEN) % Cout;
    const int b = idx / (LEN * Cout);

    double acc = (double)bias[o];
    #pragma unroll 4
    for (int i = 0; i < Ci; ++i) {
        const float* wp = &w[(o * Ci + i) * 3];
        const Tin* xp = &x[((size_t)b * Ci + i) * LEN + l];
        if (l > 0)       acc += (double)wp[0] * (double)xp[-1];
                         acc += (double)wp[1] * (double)xp[0];
        if (l < LEN - 1) acc += (double)wp[2] * (double)xp[1];
    }
    if (ACT == 1) acc = acc > 0.0 ? acc : 0.0;
    else if (ACT == 2) acc = tanh(acc);
    y[idx] = acc;
}

__global__ void zero_f64(double* __restrict__ p, int n) {
    int i = blockIdx.x * 256 + threadIdx.x;
    if (i < n) p[i] = 0.0;
}

// ---------------------------------------------------------------------------
// One coRNN step, fp64, LDS-tiled + register-blocked.
// Block: 256 threads covering (b, all 128 o, TL=16 l).
//   thread: lt = tid&3 (4 l-subtiles of 4), o0 = (tid>>2)*2 (2 o's/thread)
// LDS: hy/hz tiles [128][TL+2] fp64 (36.9 KB) -> 2 blocks/CU, 8 waves/CU.
// Per channel i: 12 LDS doubles + 12 weight floats -> 48 fp64 FMAs.
// ---------------------------------------------------------------------------
__global__ __launch_bounds__(256, 2)
void rnn_step(const double* __restrict__ hy, const double* __restrict__ hz,
              const double* __restrict__ om, const double* __restrict__ al,
              const double* __restrict__ xd,
              const float* __restrict__ wy, const float* __restrict__ by,
              const float* __restrict__ wz, const float* __restrict__ bz,
              double* __restrict__ hyo, double* __restrict__ hzo,
              float* __restrict__ yseq, int t) {
    const int l0 = blockIdx.x * TL;
    const int b  = blockIdx.y;
    const int tid = threadIdx.x;
    const int lt = tid & 3;
    const int o0 = (tid >> 2) * 2;
    const size_t base = (size_t)b * C_OUT * LEN;

    __shared__ double hys[C_OUT][TL + 2];
    __shared__ double hzs[C_OUT][TL + 2];
    for (int k = tid; k < C_OUT * (TL + 2); k += 256) {
        const int i = k / (TL + 2);
        const int j = k - i * (TL + 2);
        const int gl = l0 + j - 1;
        const bool ok = (gl >= 0) && (gl < LEN);
        const size_t gi = base + (size_t)i * LEN + gl;
        hys[i][j] = ok ? hy[gi] : 0.0;
        hzs[i][j] = ok ? hz[gi] : 0.0;
    }
    __syncthreads();

    double ay[2][4], az[2][4];
    #pragma unroll
    for (int oo = 0; oo < 2; ++oo) {
        const double vy = (double)by[o0 + oo];
        const double vz = (double)bz[o0 + oo];
        #pragma unroll
        for (int ll = 0; ll < 4; ++ll) { ay[oo][ll] = vy; az[oo][ll] = vz; }
    }

    const int lb = lt * 4;
    #pragma unroll 4
    for (int i = 0; i < C_OUT; ++i) {
        double hv[6], zv[6];
        #pragma unroll
        for (int c = 0; c < 6; ++c) { hv[c] = hys[i][lb + c]; zv[c] = hzs[i][lb + c]; }
        #pragma unroll
        for (int oo = 0; oo < 2; ++oo) {
            const float* wyp = &wy[((o0 + oo) * C_OUT + i) * 3];
            const float* wzp = &wz[((o0 + oo) * C_OUT + i) * 3];
            const double w0 = (double)wyp[0], w1 = (double)wyp[1], w2 = (double)wyp[2];
            const double v0 = (double)wzp[0], v1 = (double)wzp[1], v2 = (double)wzp[2];
            #pragma unroll
            for (int ll = 0; ll < 4; ++ll) {
                ay[oo][ll] += w0 * hv[ll] + w1 * hv[ll + 1] + w2 * hv[ll + 2];
                az[oo][ll] += v0 * zv[ll] + v1 * zv[ll + 1] + v2 * zv[ll + 2];
            }
        }
    }

    #pragma unroll
    for (int oo = 0; oo < 2; ++oo) {
        const int o = o0 + oo;
        #pragma unroll
        for (int ll = 0; ll < 4; ++ll) {
            const int l = l0 + lb + ll;
            const size_t idx = base + (size_t)o * LEN + l;
            const double hyv = hys[o][lb + ll + 1];
            const double hzv = hzs[o][lb + ll + 1];
            const double pre = tanh(ay[oo][ll] + az[oo][ll] + xd[idx]);
            const double hzn = hzv + 0.5 * (pre - om[idx] * hyv - al[idx] * hzv);
            const double hyn = hyv + 0.5 * hzn;
            hzo[idx] = hzn;
            hyo[idx] = hyn;
            yseq[((size_t)(b * TSTEPS + t) * C_OUT + o) * LEN + l] = (float)hyn;
        }
    }
}

// ---------------------------------------------------------------------------
// Readout: feat = mean_L(hy_T); 3-layer MLP (fp64); fp32 predictions.
// ---------------------------------------------------------------------------
__global__ void readout(const double* __restrict__ hyT,
                        const float* __restrict__ fw1, const float* __restrict__ fb1,
                        const float* __restrict__ fw2, const float* __restrict__ fb2,
                        const float* __restrict__ fw3, const float* __restrict__ fb3,
                        float* __restrict__ pred) {
    const int b = blockIdx.x;
    const int t = threadIdx.x;  // 128 threads
    __shared__ double feat[C_OUT];
    __shared__ double h1[64];
    __shared__ double h2[32];

    {
        double s = 0.0;
        const double* p = &hyT[((size_t)b * C_OUT + t) * LEN];
        for (int l = 0; l < LEN; ++l) s += p[l];
        feat[t] = s * (1.0 / LEN);
    }
    __syncthreads();
    if (t < 64) {
        double s = (double)fb1[t];
        for (int i = 0; i < C_OUT; ++i) s += (double)fw1[t * C_OUT + i] * feat[i];
        h1[t] = s > 0.0 ? s : 0.0;
    }
    __syncthreads();
    if (t < 32) {
        double s = (double)fb2[t];
        for (int i = 0; i < 64; ++i) s += (double)fw2[t * 64 + i] * h1[i];
        h2[t] = s > 0.0 ? s : 0.0;
    }
    __syncthreads();
    if (t < HZN) {
        double s = (double)fb3[t];
        for (int i = 0; i < 32; ++i) s += (double)fw3[t * 32 + i] * h2[i];
        pred[b * HZN + t] = (float)s;
    }
}

// ---------------------------------------------------------------------------
extern "C" void kernel_launch(void* const* d_in, const int* in_sizes, int n_in,
                              void* d_out, int out_size, void* d_ws, size_t ws_size,
                              hipStream_t stream) {
    const float* x   = (const float*)d_in[0];
    const float* ow1 = (const float*)d_in[1];  const float* ob1 = (const float*)d_in[2];
    const float* ow2 = (const float*)d_in[3];  const float* ob2 = (const float*)d_in[4];
    const float* ow3 = (const float*)d_in[5];  const float* ob3 = (const float*)d_in[6];
    const float* aw1 = (const float*)d_in[7];  const float* ab1 = (const float*)d_in[8];
    const float* aw2 = (const float*)d_in[9];  const float* ab2 = (const float*)d_in[10];
    const float* aw3 = (const float*)d_in[11]; const float* ab3 = (const float*)d_in[12];
    const float* hw1 = (const float*)d_in[13]; const float* hb1 = (const float*)d_in[14];
    const float* hw2 = (const float*)d_in[15]; const float* hb2 = (const float*)d_in[16];
    const float* hw3 = (const float*)d_in[17]; const float* hb3 = (const float*)d_in[18];
    const float* hw4 = (const float*)d_in[19]; const float* hb4 = (const float*)d_in[20];
    const float* cwy = (const float*)d_in[21]; const float* cby = (const float*)d_in[22];
    const float* cwz = (const float*)d_in[23]; const float* cbz = (const float*)d_in[24];
    const float* cwx = (const float*)d_in[25]; const float* cbx = (const float*)d_in[26];
    const float* fw1 = (const float*)d_in[27]; const float* fb1 = (const float*)d_in[28];
    const float* fw2 = (const float*)d_in[29]; const float* fb2 = (const float*)d_in[30];
    const float* fw3 = (const float*)d_in[31]; const float* fb3 = (const float*)d_in[32];

    float* out  = (float*)d_out;
    float* pred = out;                    // (B, HZN) fp32
    float* yseq = out + BATCH * HZN;      // (B, T, C_OUT, LEN) fp32

    // workspace: 7 fp64 state buffers (8 MB each = 56 MB total).
    // Encoder temps alias hyB/hzB (unused until the recurrence starts).
    const size_t SZ = (size_t)BATCH * C_OUT * LEN;  // 1,048,576 elements
    double* ws  = (double*)d_ws;
    double* om  = ws + 0 * SZ;
    double* al  = ws + 1 * SZ;
    double* xd  = ws + 2 * SZ;
    double* hyA = ws + 3 * SZ;
    double* hzA = ws + 4 * SZ;
    double* hyB = ws + 5 * SZ;
    double* hzB = ws + 6 * SZ;
    double* t1  = hyB;  // (B, C_MID, L) = 4 MB, fits in 8 MB
    double* t2  = hzB;

    const int gm = (BATCH * C_MID * LEN + 255) / 256;  // 2048 blocks
    const int go = (BATCH * C_OUT * LEN + 255) / 256;  // 4096 blocks

    // omega encoder
    enc_conv<float,  C_IN,  C_MID, 1><<<gm, 256, 0, stream>>>(x,  ow1, ob1, t1);
    enc_conv<double, C_MID, C_MID, 1><<<gm, 256, 0, stream>>>(t1, ow2, ob2, t2);
    enc_conv<double, C_MID, C_OUT, 1><<<go, 256, 0, stream>>>(t2, ow3, ob3, om);
    // alpha encoder
    enc_conv<float,  C_IN,  C_MID, 1><<<gm, 256, 0, stream>>>(x,  aw1, ab1, t1);
    enc_conv<double, C_MID, C_MID, 1><<<gm, 256, 0, stream>>>(t1, aw2, ab2, t2);
    enc_conv<double, C_MID, C_OUT, 1><<<go, 256, 0, stream>>>(t2, aw3, ab3, al);
    // hy encoder
    enc_conv<float,  C_IN,  C_MID, 1><<<gm, 256, 0, stream>>>(x,  hw1, hb1, t1);
    enc_conv<double, C_MID, C_MID, 1><<<gm, 256, 0, stream>>>(t1, hw2, hb2, t2);
    enc_conv<double, C_MID, C_MID, 1><<<gm, 256, 0, stream>>>(t2, hw3, hb3, t1);
    enc_conv<double, C_MID, C_OUT, 2><<<go, 256, 0, stream>>>(t1, hw4, hb4, hyA);
    // x drive (no activation)
    enc_conv<float,  C_IN,  C_OUT, 0><<<go, 256, 0, stream>>>(x, cwx, cbx, xd);
    // hz0 = 0
    zero_f64<<<go, 256, 0, stream>>>(hzA, (int)SZ);

    // recurrence (note: step 0 overwrites hyB/hzB, which held encoder temps)
    double* hy_cur = hyA; double* hz_cur = hzA;
    double* hy_nxt = hyB; double* hz_nxt = hzB;
    dim3 sgrid(LEN / TL, BATCH);
    for (int t = 0; t < TSTEPS; ++t) {
        rnn_step<<<sgrid, 256, 0, stream>>>(hy_cur, hz_cur, om, al, xd,
                                            cwy, cby, cwz, cbz,
                                            hy_nxt, hz_nxt, yseq, t);
        double* sy = hy_cur; hy_cur = hy_nxt; hy_nxt = sy;
        double* sz = hz_cur; hz_cur = hz_nxt; hz_nxt = sz;
    }

    // readout on final hy
    readout<<<BATCH, C_OUT, 0, stream>>>(hy_cur, fw1, fb1, fw2, fb2, fw3, fb3, pred);
}